// Round 1
// baseline (1742.766 us; speedup 1.0000x reference)
//
#include <hip/hip_runtime.h>

typedef __bf16 bf16;
typedef __bf16 bf16x8 __attribute__((ext_vector_type(8)));
typedef float f32x4 __attribute__((ext_vector_type(4)));

#define GLL16(gp, lp) __builtin_amdgcn_global_load_lds( \
    (__attribute__((address_space(1))) void*)(gp), \
    (__attribute__((address_space(3))) void*)(lp), 16, 0, 0)

// ---------------- conversion kernels ----------------
__global__ void cvt_kernel(const float* __restrict__ src, bf16* __restrict__ dst, int n) {
    int i = blockIdx.x * 256 + threadIdx.x;
    if (i < n) dst[i] = (bf16)src[i];
}

// src [3*512][512] rows g*512+d  ->  dst rows 3*d+g (bf16)
__global__ void cvt_interleave_kernel(const float* __restrict__ src, bf16* __restrict__ dst) {
    int i = blockIdx.x * 256 + threadIdx.x;   // 0 .. 786431
    int row = i >> 9, c = i & 511;
    int g = row % 3, d = row / 3;
    dst[i] = (bf16)src[(g * 512 + d) * 512 + c];
}

// ---------------- conv1: x fp32 [26624,8192] @ w1^T [256,8192] -> h1 bf16 [26624,256]
// tile 64x256 (full N per block so x is read once), fused fp32->bf16 staging
__global__ __launch_bounds__(256) void conv1_kernel(
    const float* __restrict__ A, const bf16* __restrict__ B,
    const float* __restrict__ bias, bf16* __restrict__ out)
{
    const int K = 8192;
    __shared__ __align__(16) bf16 As[64 * 32];
    __shared__ __align__(16) bf16 Bs[256 * 32];
    const int tid = threadIdx.x;
    const int wave = tid >> 6, lane = tid & 63;
    const int quad = lane >> 4, l16 = lane & 15;
    const int wm = (wave & 1) * 32, wn = (wave >> 1) * 128;
    const int m0 = blockIdx.x * 64;
    const int ar = tid >> 2, akq = tid & 3;

    f32x4 acc[2][8] = {};
    const float* agp = A + (size_t)(m0 + ar) * K + akq * 8;

    for (int kt = 0; kt < K; kt += 32) {
        // A staging: 8 fp32 -> 8 bf16 per thread
        const float4* ap = (const float4*)(agp + kt);
        float4 p0 = ap[0], p1 = ap[1];
        bf16x8 v;
        v[0]=(bf16)p0.x; v[1]=(bf16)p0.y; v[2]=(bf16)p0.z; v[3]=(bf16)p0.w;
        v[4]=(bf16)p1.x; v[5]=(bf16)p1.y; v[6]=(bf16)p1.z; v[7]=(bf16)p1.w;
        *(bf16x8*)(As + tid * 8) = v;
        // B staging: 256x32 bf16 = 16KB via 4 async issues
        #pragma unroll
        for (int s = 0; s < 4; ++s) {
            int c = tid + s * 256;
            GLL16(B + (size_t)(c >> 2) * K + kt + (c & 3) * 8, Bs + c * 8);
        }
        __syncthreads();
        bf16x8 af[2], bfr[8];
        #pragma unroll
        for (int i = 0; i < 2; ++i)
            af[i] = *(const bf16x8*)(As + (wm + i * 16 + l16) * 32 + quad * 8);
        #pragma unroll
        for (int j = 0; j < 8; ++j)
            bfr[j] = *(const bf16x8*)(Bs + (wn + j * 16 + l16) * 32 + quad * 8);
        #pragma unroll
        for (int i = 0; i < 2; ++i)
            #pragma unroll
            for (int j = 0; j < 8; ++j)
                acc[i][j] = __builtin_amdgcn_mfma_f32_16x16x32_bf16(af[i], bfr[j], acc[i][j], 0, 0, 0);
        __syncthreads();
    }
    #pragma unroll
    for (int i = 0; i < 2; ++i)
        #pragma unroll
        for (int j = 0; j < 8; ++j)
            #pragma unroll
            for (int r = 0; r < 4; ++r) {
                int row = m0 + wm + i * 16 + quad * 4 + r;
                int col = wn + j * 16 + l16;
                float v2 = acc[i][j][r] + bias[col];
                v2 = (v2 > 1e-6f) ? v2 : 0.0f;
                out[(size_t)row * 256 + col] = (bf16)v2;
            }
}

// ---------------- generic 128x128 bf16 GEMM: C = A[M,K] @ B[N,K]^T + bias
// mode 0: bias + threshold, bf16 out   (conv2)
// mode 1: interleaved bias (g=col%3,d=col/3), bf16 out   (gi)
// mode 2: bias, fp32 out   (final linear)
__global__ __launch_bounds__(256) void gemm128_kernel(
    const bf16* __restrict__ A, const bf16* __restrict__ B,
    const float* __restrict__ bias, bf16* __restrict__ outh,
    float* __restrict__ outf, int M, int N, int K, int mode)
{
    __shared__ __align__(16) bf16 As[128 * 32];
    __shared__ __align__(16) bf16 Bs[128 * 32];
    const int tid = threadIdx.x;
    const int wave = tid >> 6, lane = tid & 63;
    const int quad = lane >> 4, l16 = lane & 15;
    const int wm = (wave & 1) * 64, wn = (wave >> 1) * 64;
    const int m0 = blockIdx.y * 128, n0 = blockIdx.x * 128;
    const int ar = tid >> 2, akq = tid & 3;

    f32x4 acc[4][4] = {};

    for (int kt = 0; kt < K; kt += 32) {
        GLL16(A + (size_t)(m0 + ar) * K + kt + akq * 8, As + tid * 8);
        GLL16(A + (size_t)(m0 + 64 + ar) * K + kt + akq * 8, As + 2048 + tid * 8);
        GLL16(B + (size_t)(n0 + ar) * K + kt + akq * 8, Bs + tid * 8);
        GLL16(B + (size_t)(n0 + 64 + ar) * K + kt + akq * 8, Bs + 2048 + tid * 8);
        __syncthreads();
        bf16x8 af[4], bfr[4];
        #pragma unroll
        for (int i = 0; i < 4; ++i) {
            af[i]  = *(const bf16x8*)(As + (wm + i * 16 + l16) * 32 + quad * 8);
            bfr[i] = *(const bf16x8*)(Bs + (wn + i * 16 + l16) * 32 + quad * 8);
        }
        #pragma unroll
        for (int i = 0; i < 4; ++i)
            #pragma unroll
            for (int j = 0; j < 4; ++j)
                acc[i][j] = __builtin_amdgcn_mfma_f32_16x16x32_bf16(af[i], bfr[j], acc[i][j], 0, 0, 0);
        __syncthreads();
    }
    #pragma unroll
    for (int i = 0; i < 4; ++i)
        #pragma unroll
        for (int j = 0; j < 4; ++j)
            #pragma unroll
            for (int r = 0; r < 4; ++r) {
                int row = m0 + wm + i * 16 + quad * 4 + r;
                int col = n0 + wn + j * 16 + l16;
                float v = acc[i][j][r];
                if (mode == 1) { int g = col % 3, d = col / 3; v += bias[g * 512 + d]; }
                else v += bias[col];
                if (mode == 0) v = (v > 1e-6f) ? v : 0.0f;
                if (mode == 2) outf[(size_t)row * N + col] = v;
                else outh[(size_t)row * N + col] = (bf16)v;
            }
}

// ---------------- fused GRU step: gh = h_prev @ whh'(interleaved)^T + b_hh, gates, h_new
// tile 64 x 96 (=32 complete d-groups), grid (16,16)
__global__ __launch_bounds__(256) void gru_step_kernel(
    const bf16* __restrict__ gi,    // [26624,1536] interleaved cols (incl. b_ih)
    const bf16* __restrict__ whh,   // [1536,512] interleaved rows
    const float* __restrict__ bhh,  // [1536] original layout
    const bf16* __restrict__ hprev, // [1024,512]
    bf16* __restrict__ hout,        // [1024,512]
    int t, int first)
{
    const int K = 512;
    __shared__ __align__(16) char smem[64 * 100 * 4];  // 25600 B, unioned
    bf16* As = (bf16*)smem;                 // 64*32 bf16 = 4 KB
    bf16* Bs = (bf16*)(smem + 4096);        // 96*32 bf16 = 6 KB
    float* ghs = (float*)smem;              // 64 x 100 fp32 (padded stride)

    const int tid = threadIdx.x;
    const int wave = tid >> 6, lane = tid & 63;
    const int quad = lane >> 4, l16 = lane & 15;
    const int wm = (wave & 1) * 32, wn = (wave >> 1) * 48;
    const int nb = blockIdx.x, mb = blockIdx.y;
    const int m0 = mb * 64, n0 = nb * 96;

    if (!first) {
        f32x4 acc[2][3] = {};
        const int ar = tid >> 2, akq = tid & 3;
        for (int kt = 0; kt < K; kt += 32) {
            GLL16(hprev + (size_t)(m0 + ar) * K + kt + akq * 8, As + tid * 8);
            GLL16(whh + (size_t)(n0 + ar) * K + kt + akq * 8, Bs + tid * 8);
            if (tid < 128) {
                int c = 256 + tid;
                GLL16(whh + (size_t)(n0 + (c >> 2)) * K + kt + (c & 3) * 8, Bs + c * 8);
            }
            __syncthreads();
            bf16x8 af[2], bfr[3];
            #pragma unroll
            for (int i = 0; i < 2; ++i)
                af[i] = *(const bf16x8*)(As + (wm + i * 16 + l16) * 32 + quad * 8);
            #pragma unroll
            for (int j = 0; j < 3; ++j)
                bfr[j] = *(const bf16x8*)(Bs + (wn + j * 16 + l16) * 32 + quad * 8);
            #pragma unroll
            for (int i = 0; i < 2; ++i)
                #pragma unroll
                for (int j = 0; j < 3; ++j)
                    acc[i][j] = __builtin_amdgcn_mfma_f32_16x16x32_bf16(af[i], bfr[j], acc[i][j], 0, 0, 0);
            __syncthreads();
        }
        // gh + b_hh -> LDS (fp32, padded stride 100 to dodge bank conflicts)
        #pragma unroll
        for (int i = 0; i < 2; ++i)
            #pragma unroll
            for (int j = 0; j < 3; ++j)
                #pragma unroll
                for (int r = 0; r < 4; ++r) {
                    int lrow = wm + i * 16 + quad * 4 + r;
                    int lcol = wn + j * 16 + l16;
                    int g = lcol % 3;                // n0 divisible by 3
                    int dg = nb * 32 + lcol / 3;
                    ghs[lrow * 100 + lcol] = acc[i][j][r] + bhh[g * 512 + dg];
                }
    }
    __syncthreads();

    // gate phase: 64 rows x 32 d per block
    for (int it = 0; it < 8; ++it) {
        int item = it * 256 + tid;
        int lrow = item >> 5, ld = item & 31;
        int b = m0 + lrow;
        int dg = nb * 32 + ld;
        float ghr, ghz, ghn;
        if (first) { ghr = bhh[dg]; ghz = bhh[512 + dg]; ghn = bhh[1024 + dg]; }
        else {
            ghr = ghs[lrow * 100 + ld * 3];
            ghz = ghs[lrow * 100 + ld * 3 + 1];
            ghn = ghs[lrow * 100 + ld * 3 + 2];
        }
        size_t gb = ((size_t)b * 26 + t) * 1536 + n0 + ld * 3;
        float gir = (float)gi[gb], giz = (float)gi[gb + 1], gin = (float)gi[gb + 2];
        float hp = first ? 0.0f : (float)hprev[(size_t)b * 512 + dg];
        float rr = 1.0f / (1.0f + __expf(-(gir + ghr)));
        float zz = 1.0f / (1.0f + __expf(-(giz + ghz)));
        float nn = tanhf(gin + rr * ghn);
        hout[(size_t)b * 512 + dg] = (bf16)((1.0f - zz) * nn + zz * hp);
    }
}

extern "C" void kernel_launch(void* const* d_in, const int* in_sizes, int n_in,
                              void* d_out, int out_size, void* d_ws, size_t ws_size,
                              hipStream_t stream) {
    const float* x       = (const float*)d_in[0];
    const float* conv1_w = (const float*)d_in[1];
    const float* conv1_b = (const float*)d_in[2];
    const float* conv2_w = (const float*)d_in[3];
    const float* conv2_b = (const float*)d_in[4];
    const float* w_ih    = (const float*)d_in[5];
    const float* w_hh    = (const float*)d_in[6];
    const float* b_ih    = (const float*)d_in[7];
    const float* b_hh    = (const float*)d_in[8];
    const float* lin_w   = (const float*)d_in[9];
    const float* lin_b   = (const float*)d_in[10];
    float* out = (float*)d_out;

    // workspace layout (bf16 elems), total ~133.4 MB
    bf16* ws   = (bf16*)d_ws;
    bf16* w1   = ws;                 // 256*8192
    bf16* w2   = w1  + 2097152;      // 512*256
    bf16* wih  = w2  + 131072;       // 1536*512 interleaved
    bf16* whh  = wih + 786432;       // 1536*512 interleaved
    bf16* wlin = whh + 786432;       // 1024*512
    bf16* h1   = wlin + 524288;      // 26624*256
    bf16* h2   = h1  + 6815744;      // 26624*512
    bf16* gib  = h2  + 13631488;     // 26624*1536
    bf16* H0   = gib + 40894464;     // 1024*512
    bf16* H1   = H0  + 524288;       // 1024*512

    cvt_kernel<<<8192, 256, 0, stream>>>(conv1_w, w1, 2097152);
    cvt_kernel<<<512, 256, 0, stream>>>(conv2_w, w2, 131072);
    cvt_interleave_kernel<<<3072, 256, 0, stream>>>(w_ih, wih);
    cvt_interleave_kernel<<<3072, 256, 0, stream>>>(w_hh, whh);
    cvt_kernel<<<2048, 256, 0, stream>>>(lin_w, wlin, 524288);

    // conv1: [26624,8192] -> [26624,256]
    conv1_kernel<<<416, 256, 0, stream>>>(x, w1, conv1_b, h1);
    // conv2: [26624,256] -> [26624,512]
    gemm128_kernel<<<dim3(4, 208), 256, 0, stream>>>(h1, w2, conv2_b, h2, nullptr, 26624, 512, 256, 0);
    // gi = h2 @ w_ih'^T + b_ih (interleaved cols): [26624,1536]
    gemm128_kernel<<<dim3(12, 208), 256, 0, stream>>>(h2, wih, b_ih, gib, nullptr, 26624, 1536, 512, 1);
    // 26 fused GRU steps, ping-pong H0/H1; t=0 skips GEMM (h0 = 0)
    for (int t = 0; t < 26; ++t) {
        const bf16* hp = (t & 1) ? H1 : H0;
        bf16* ho = (t & 1) ? H0 : H1;
        gru_step_kernel<<<dim3(16, 16), 256, 0, stream>>>(gib, whh, b_hh, hp, ho, t, t == 0);
    }
    // final: H0 [1024,512] @ lin_w^T -> out fp32 [1024,1024]
    gemm128_kernel<<<dim3(8, 8), 256, 0, stream>>>(H0, wlin, lin_b, nullptr, out, 1024, 1024, 512, 2);
}

// Round 2
// 1727.758 us; speedup vs baseline: 1.0087x; 1.0087x over previous
//
#include <hip/hip_runtime.h>

typedef __bf16 bf16;
typedef __bf16 bf16x8 __attribute__((ext_vector_type(8)));
typedef __bf16 bf16x4 __attribute__((ext_vector_type(4)));
typedef float f32x4 __attribute__((ext_vector_type(4)));

#define GLL16(gp, lp) __builtin_amdgcn_global_load_lds( \
    (__attribute__((address_space(1))) void*)(gp), \
    (__attribute__((address_space(3))) void*)(lp), 16, 0, 0)

// ---------------- fused weight conversion (all 5 weight mats -> contiguous bf16) ----
__global__ void cvt_all_kernel(const float* __restrict__ a, const float* __restrict__ b,
                               const float* __restrict__ c, const float* __restrict__ d,
                               const float* __restrict__ e, bf16* __restrict__ dst) {
    int i = blockIdx.x * 256 + threadIdx.x;
    float v;
    if      (i < 2097152) v = a[i];
    else if (i < 2228224) v = b[i - 2097152];
    else if (i < 3014656) v = c[i - 2228224];
    else if (i < 3801088) v = d[i - 3014656];
    else if (i < 4325376) v = e[i - 3801088];
    else return;
    dst[i] = (bf16)v;
}

// ---------------- conv1 split-K: x fp32 [26624,8192] @ w1^T [256,8192] -> fp32 partials
// grid (416, 4): 64-row tile x full N=256, K-slice 2048 per block -> 6.5 blocks/CU
__global__ __launch_bounds__(256) void conv1_kernel(
    const float* __restrict__ A, const bf16* __restrict__ B, float* __restrict__ P)
{
    const int K = 8192;
    __shared__ __align__(16) bf16 As[64 * 32];
    __shared__ __align__(16) bf16 Bs[256 * 32];
    const int tid = threadIdx.x;
    const int wave = tid >> 6, lane = tid & 63;
    const int quad = lane >> 4, l16 = lane & 15;
    const int wm = (wave & 1) * 32, wn = (wave >> 1) * 128;
    const int m0 = blockIdx.x * 64;
    const int k0 = blockIdx.y * 2048;
    const int ar = tid >> 2, akq = tid & 3;

    f32x4 acc[2][8] = {};
    const float* agp = A + (size_t)(m0 + ar) * K + akq * 8;

    for (int kt = k0; kt < k0 + 2048; kt += 32) {
        const float4* ap = (const float4*)(agp + kt);
        float4 p0 = ap[0], p1 = ap[1];
        bf16x8 v;
        v[0]=(bf16)p0.x; v[1]=(bf16)p0.y; v[2]=(bf16)p0.z; v[3]=(bf16)p0.w;
        v[4]=(bf16)p1.x; v[5]=(bf16)p1.y; v[6]=(bf16)p1.z; v[7]=(bf16)p1.w;
        *(bf16x8*)(As + tid * 8) = v;
        #pragma unroll
        for (int s = 0; s < 4; ++s) {
            int c = tid + s * 256;
            GLL16(B + (size_t)(c >> 2) * K + kt + (c & 3) * 8, Bs + c * 8);
        }
        __syncthreads();
        bf16x8 af[2], bfr[8];
        #pragma unroll
        for (int i = 0; i < 2; ++i)
            af[i] = *(const bf16x8*)(As + (wm + i * 16 + l16) * 32 + quad * 8);
        #pragma unroll
        for (int j = 0; j < 8; ++j)
            bfr[j] = *(const bf16x8*)(Bs + (wn + j * 16 + l16) * 32 + quad * 8);
        #pragma unroll
        for (int i = 0; i < 2; ++i)
            #pragma unroll
            for (int j = 0; j < 8; ++j)
                acc[i][j] = __builtin_amdgcn_mfma_f32_16x16x32_bf16(af[i], bfr[j], acc[i][j], 0, 0, 0);
        __syncthreads();
    }
    float* Pp = P + (size_t)blockIdx.y * 26624 * 256;
    #pragma unroll
    for (int i = 0; i < 2; ++i)
        #pragma unroll
        for (int j = 0; j < 8; ++j)
            #pragma unroll
            for (int r = 0; r < 4; ++r) {
                int row = m0 + wm + i * 16 + quad * 4 + r;
                int col = wn + j * 16 + l16;
                Pp[(size_t)row * 256 + col] = acc[i][j][r];
            }
}

// reduce 4 partial planes + bias + threshold -> bf16 h1
__global__ void conv1_reduce_kernel(const float* __restrict__ P, const float* __restrict__ bias,
                                    bf16* __restrict__ out) {
    const size_t plane = 26624ull * 256 / 4;   // float4 units
    size_t i = blockIdx.x * 256 + threadIdx.x; // 0 .. 1703935
    const float4* p = (const float4*)P;
    float4 s0 = p[i], s1 = p[i + plane], s2 = p[i + 2 * plane], s3 = p[i + 3 * plane];
    int col = (int)((i * 4) & 255);
    float4 bb = *(const float4*)(bias + col);
    float r0 = s0.x + s1.x + s2.x + s3.x + bb.x;
    float r1 = s0.y + s1.y + s2.y + s3.y + bb.y;
    float r2 = s0.z + s1.z + s2.z + s3.z + bb.z;
    float r3 = s0.w + s1.w + s2.w + s3.w + bb.w;
    bf16x4 o;
    o[0] = (bf16)(r0 > 1e-6f ? r0 : 0.0f);
    o[1] = (bf16)(r1 > 1e-6f ? r1 : 0.0f);
    o[2] = (bf16)(r2 > 1e-6f ? r2 : 0.0f);
    o[3] = (bf16)(r3 > 1e-6f ? r3 : 0.0f);
    *(bf16x4*)(out + i * 4) = o;
}

// ---------------- generic 128x128 bf16 GEMM: C = A[M,K] @ B[N,K]^T + bias
// mode 0: bias + threshold, bf16 out (conv2) | mode 1: bias, bf16 out (gi) | mode 2: bias, fp32 out
__global__ __launch_bounds__(256) void gemm128_kernel(
    const bf16* __restrict__ A, const bf16* __restrict__ B,
    const float* __restrict__ bias, bf16* __restrict__ outh,
    float* __restrict__ outf, int M, int N, int K, int mode)
{
    __shared__ __align__(16) bf16 As[128 * 32];
    __shared__ __align__(16) bf16 Bs[128 * 32];
    const int tid = threadIdx.x;
    const int wave = tid >> 6, lane = tid & 63;
    const int quad = lane >> 4, l16 = lane & 15;
    const int wm = (wave & 1) * 64, wn = (wave >> 1) * 64;
    const int m0 = blockIdx.y * 128, n0 = blockIdx.x * 128;
    const int ar = tid >> 2, akq = tid & 3;

    f32x4 acc[4][4] = {};

    for (int kt = 0; kt < K; kt += 32) {
        GLL16(A + (size_t)(m0 + ar) * K + kt + akq * 8, As + tid * 8);
        GLL16(A + (size_t)(m0 + 64 + ar) * K + kt + akq * 8, As + 2048 + tid * 8);
        GLL16(B + (size_t)(n0 + ar) * K + kt + akq * 8, Bs + tid * 8);
        GLL16(B + (size_t)(n0 + 64 + ar) * K + kt + akq * 8, Bs + 2048 + tid * 8);
        __syncthreads();
        bf16x8 af[4], bfr[4];
        #pragma unroll
        for (int i = 0; i < 4; ++i) {
            af[i]  = *(const bf16x8*)(As + (wm + i * 16 + l16) * 32 + quad * 8);
            bfr[i] = *(const bf16x8*)(Bs + (wn + i * 16 + l16) * 32 + quad * 8);
        }
        #pragma unroll
        for (int i = 0; i < 4; ++i)
            #pragma unroll
            for (int j = 0; j < 4; ++j)
                acc[i][j] = __builtin_amdgcn_mfma_f32_16x16x32_bf16(af[i], bfr[j], acc[i][j], 0, 0, 0);
        __syncthreads();
    }
    #pragma unroll
    for (int i = 0; i < 4; ++i)
        #pragma unroll
        for (int j = 0; j < 4; ++j)
            #pragma unroll
            for (int r = 0; r < 4; ++r) {
                int row = m0 + wm + i * 16 + quad * 4 + r;
                int col = n0 + wn + j * 16 + l16;
                float v = acc[i][j][r] + bias[col];
                if (mode == 0) v = (v > 1e-6f) ? v : 0.0f;
                if (mode == 2) outf[(size_t)row * N + col] = v;
                else outh[(size_t)row * N + col] = (bf16)v;
            }
}

// ---------------- GRU step v2: whh tile resident in LDS (padded), barrier-free K-loop,
// planar gi/whh (no interleave). grid (16 nb, 16 mb), 256 thr.
__global__ __launch_bounds__(256) void gru_step_kernel(
    const bf16* __restrict__ gi,    // [26624,1536] planar cols (r|z|n planes of 512)
    const bf16* __restrict__ whh,   // [1536,512] original layout
    const float* __restrict__ bhh,  // [1536]
    const bf16* __restrict__ hprev, // [1024,512]
    bf16* __restrict__ hout,        // [1024,512]
    int t, int first)
{
    __shared__ __align__(16) char smem[99840];   // whhS 96x520 bf16 | reused as ghs 64x100 f32
    const int tid = threadIdx.x;
    const int wave = tid >> 6, lane = tid & 63;
    const int quad = lane >> 4, l16 = lane & 15;
    const int wm = (wave & 1) * 32, wn = (wave >> 1) * 48;
    const int nb = blockIdx.x, mb = blockIdx.y;
    const int m0 = mb * 64;
    float* ghs = (float*)smem;

    if (!first) {
        bf16* ws = (bf16*)smem;
        // stage whh rows {d, 512+d, 1024+d : d in [nb*32, nb*32+32)} -> 96 x (512 pad 520)
        bf16x8 tmp[24];
        #pragma unroll
        for (int ii = 0; ii < 24; ++ii) {
            int cc = ii * 256 + tid;        // 16B chunk id, 64 chunks/row
            int row = cc >> 6;
            int col = (cc & 63) * 8;
            int gr = (row < 32) ? nb * 32 + row
                   : (row < 64) ? 512 + nb * 32 + (row - 32)
                                : 1024 + nb * 32 + (row - 64);
            tmp[ii] = *(const bf16x8*)(whh + (size_t)gr * 512 + col);
        }
        #pragma unroll
        for (int ii = 0; ii < 24; ++ii) {
            int cc = ii * 256 + tid;
            int row = cc >> 6;
            int col = (cc & 63) * 8;
            *(bf16x8*)(ws + row * 520 + col) = tmp[ii];
        }
        __syncthreads();

        f32x4 acc[2][3] = {};
        #pragma unroll
        for (int kt = 0; kt < 512; kt += 32) {
            bf16x8 af[2], bfr[3];
            #pragma unroll
            for (int i = 0; i < 2; ++i)
                af[i] = *(const bf16x8*)(hprev + (size_t)(m0 + wm + i * 16 + l16) * 512 + kt + quad * 8);
            #pragma unroll
            for (int j = 0; j < 3; ++j)
                bfr[j] = *(const bf16x8*)(ws + (wn + j * 16 + l16) * 520 + kt + quad * 8);
            #pragma unroll
            for (int i = 0; i < 2; ++i)
                #pragma unroll
                for (int j = 0; j < 3; ++j)
                    acc[i][j] = __builtin_amdgcn_mfma_f32_16x16x32_bf16(af[i], bfr[j], acc[i][j], 0, 0, 0);
        }
        __syncthreads();   // whhS dead; reuse as ghs
        #pragma unroll
        for (int i = 0; i < 2; ++i)
            #pragma unroll
            for (int j = 0; j < 3; ++j)
                #pragma unroll
                for (int r = 0; r < 4; ++r) {
                    int lrow = wm + i * 16 + quad * 4 + r;
                    int lcol = wn + j * 16 + l16;          // 0..95: plane = lcol/32
                    int plane = lcol >> 5, dl = lcol & 31;
                    ghs[lrow * 100 + lcol] = acc[i][j][r] + bhh[plane * 512 + nb * 32 + dl];
                }
        __syncthreads();
    }

    // gates: 64 rows x 32 d per block
    #pragma unroll
    for (int it = 0; it < 8; ++it) {
        int item = it * 256 + tid;
        int lrow = item >> 5, ld = item & 31;
        int b = m0 + lrow;
        int dg = nb * 32 + ld;
        float ghr, ghz, ghn, hp;
        if (first) { ghr = bhh[dg]; ghz = bhh[512 + dg]; ghn = bhh[1024 + dg]; hp = 0.0f; }
        else {
            ghr = ghs[lrow * 100 + ld];
            ghz = ghs[lrow * 100 + 32 + ld];
            ghn = ghs[lrow * 100 + 64 + ld];
            hp  = (float)hprev[(size_t)b * 512 + dg];
        }
        size_t gb = ((size_t)b * 26 + t) * 1536;
        float gir = (float)gi[gb + dg], giz = (float)gi[gb + 512 + dg], gin = (float)gi[gb + 1024 + dg];
        float rr = 1.0f / (1.0f + __expf(-(gir + ghr)));
        float zz = 1.0f / (1.0f + __expf(-(giz + ghz)));
        float xx = gin + rr * ghn;
        float nn = 1.0f - 2.0f / (__expf(2.0f * xx) + 1.0f);   // tanh
        hout[(size_t)b * 512 + dg] = (bf16)((1.0f - zz) * nn + zz * hp);
    }
}

extern "C" void kernel_launch(void* const* d_in, const int* in_sizes, int n_in,
                              void* d_out, int out_size, void* d_ws, size_t ws_size,
                              hipStream_t stream) {
    const float* x       = (const float*)d_in[0];
    const float* conv1_w = (const float*)d_in[1];
    const float* conv1_b = (const float*)d_in[2];
    const float* conv2_w = (const float*)d_in[3];
    const float* conv2_b = (const float*)d_in[4];
    const float* w_ih    = (const float*)d_in[5];
    const float* w_hh    = (const float*)d_in[6];
    const float* b_ih    = (const float*)d_in[7];
    const float* b_hh    = (const float*)d_in[8];
    const float* lin_w   = (const float*)d_in[9];
    const float* lin_b   = (const float*)d_in[10];
    float* out = (float*)d_out;

    // workspace: fp32 partials first (16B aligned), then bf16 region
    float* P   = (float*)d_ws;              // 4 * 26624*256 fp32 = 109 MB
    bf16* wsb  = (bf16*)(P + 4ull * 26624 * 256);
    bf16* w1   = wsb;                 // 2097152
    bf16* w2   = w1  + 2097152;       // 131072
    bf16* wih  = w2  + 131072;        // 786432
    bf16* whh  = wih + 786432;        // 786432
    bf16* wlin = whh + 786432;        // 524288
    bf16* h1   = wlin + 524288;       // 6815744
    bf16* h2   = h1  + 6815744;       // 13631488
    bf16* gib  = h2  + 13631488;      // 40894464
    bf16* H0   = gib + 40894464;      // 524288
    bf16* H1   = H0  + 524288;        // 524288

    cvt_all_kernel<<<16896, 256, 0, stream>>>(conv1_w, conv2_w, w_ih, w_hh, lin_w, w1);

    // conv1 split-K=4 + reduce
    conv1_kernel<<<dim3(416, 4), 256, 0, stream>>>(x, w1, P);
    conv1_reduce_kernel<<<6656, 256, 0, stream>>>(P, conv1_b, h1);
    // conv2: [26624,256] -> [26624,512]
    gemm128_kernel<<<dim3(4, 208), 256, 0, stream>>>(h1, w2, conv2_b, h2, nullptr, 26624, 512, 256, 0);
    // gi = h2 @ w_ih^T + b_ih (planar): [26624,1536]
    gemm128_kernel<<<dim3(12, 208), 256, 0, stream>>>(h2, wih, b_ih, gib, nullptr, 26624, 1536, 512, 1);
    // 26 GRU steps, ping-pong
    for (int t = 0; t < 26; ++t) {
        const bf16* hp = (t & 1) ? H1 : H0;
        bf16* ho = (t & 1) ? H0 : H1;
        gru_step_kernel<<<dim3(16, 16), 256, 0, stream>>>(gib, whh, b_hh, hp, ho, t, t == 0);
    }
    // final: H0 [1024,512] @ lin_w^T + b -> out fp32 [1024,1024]
    gemm128_kernel<<<dim3(8, 8), 256, 0, stream>>>(H0, wlin, lin_b, nullptr, out, 1024, 1024, 512, 2);
}